// Round 7
// baseline (3019.044 us; speedup 1.0000x reference)
//
#include <hip/hip_runtime.h>

// Problem constants
#define NPOS   158   // 64 query + 94 doc token positions per batch
#define EPITCH 136   // shorts per staged emb row (128 + 8 pad)

// workspace layout
#define RKP_SHORTS (2*64*8*512)            // rk packed: [dir][nt64][ks8][lane64][j8]
#define KP_SHORTS  (2*64*4*512)            // k  packed: [dir][nt64][ks4][lane64][j8]
#define XZ_HALFS   ((size_t)2*128*158*1024)
#define OFF_KP     ((size_t)RKP_SHORTS*2)                 // 1,048,576
#define OFF_XZ     (OFF_KP + (size_t)KP_SHORTS*2)         // 1,572,864
#define OFF_HOUT   (OFF_XZ + XZ_HALFS*2)                  // 84,410,368

typedef __attribute__((ext_vector_type(8))) short    short8;
typedef __attribute__((ext_vector_type(4))) short    short4v;
typedef __attribute__((ext_vector_type(4))) float    float4v;
typedef __attribute__((ext_vector_type(8))) _Float16 half8;

__device__ __forceinline__ unsigned short f2bf(float x){
  unsigned int u = __builtin_bit_cast(unsigned int, x);
  u += 0x7FFFu + ((u >> 16) & 1u);           // round-to-nearest-even
  return (unsigned short)(u >> 16);
}
__device__ __forceinline__ float fsig(float x){
  return 1.0f/(1.0f + __expf(-x));
}
__device__ __forceinline__ float ftanh(float x){
  float ax = fabsf(x);
  float e  = __expf(-2.0f*ax);
  float r  = (1.0f - e)/(1.0f + e);
  return (x < 0.0f) ? -r : r;
}

// ---------------------------------------------------------------------------
// Pack rk (256x1024) and k (128x1024) per dir into MFMA B-fragment lane order:
// element j of lane l for tile (nt,ks) = W[k = ks*32+(l>>4)*8+j][col = nt*16+(l&15)].
// ---------------------------------------------------------------------------
__global__ void prepack(const float* __restrict__ kf, const float* __restrict__ rkf,
                        const float* __restrict__ kb, const float* __restrict__ rkb,
                        unsigned short* __restrict__ rkp, unsigned short* __restrict__ kp){
  int idx = blockIdx.x*256 + threadIdx.x;
  if (idx < RKP_SHORTS){
    int j = idx & 7, lane = (idx>>3)&63, ks = (idx>>9)&7, nt = (idx>>12)&63, d = idx>>18;
    const float* RK = d ? rkb : rkf;
    int k   = ks*32 + (lane>>4)*8 + j;
    int col = nt*16 + (lane&15);
    rkp[idx] = f2bf(RK[k*1024 + col]);
  } else {
    int i2 = idx - RKP_SHORTS;
    if (i2 < KP_SHORTS){
      int j = i2 & 7, lane = (i2>>3)&63, ks = (i2>>9)&3, nt = (i2>>11)&63, d = i2>>17;
      const float* K = d ? kb : kf;
      int k   = ks*32 + (lane>>4)*8 + j;
      int col = nt*16 + (lane&15);
      kp[i2] = f2bf(K[k*1024 + col]);
    }
  }
}

// ---------------------------------------------------------------------------
// xz[dir][bat][pos][1024] (fp16) = emb @ k + bias, inner layout
// [pos][wv 8][lc 16][n 8], n = gate*2+tj.
// ---------------------------------------------------------------------------
__launch_bounds__(512)
__global__ void xzgemm(const int* __restrict__ inputs, const float* __restrict__ emb,
                       const unsigned short* __restrict__ kpack,
                       const float* __restrict__ b_f, const float* __restrict__ b_b,
                       _Float16* __restrict__ xz){
  __shared__ int tokp[32];
  __shared__ __align__(16) short e_lds[32*EPITCH];
  const int bid = blockIdx.x;
  const int pt  = bid % 5;
  const int bd  = bid / 5;
  const int bat = bd & 127, dir = bd >> 7;
  const int tid = threadIdx.x, lane = tid & 63, wv = tid >> 6;
  const int lc  = lane & 15, q = lane >> 4;

  for (int i = tid; i < 32*EPITCH; i += 512) e_lds[i] = 0;
  if (tid < 32){
    int p = pt*32 + tid;
    tokp[tid] = (p < NPOS) ? inputs[bat*NPOS + p] : 0;
  }
  __syncthreads();
  for (int idx = tid; idx < 32*32; idx += 512){
    int i = idx >> 5, c4 = (idx & 31) << 2;
    int p = pt*32 + i;
    if (p < NPOS){
      float4v v = *(const float4v*)(emb + (long)tokp[i]*128 + c4);
      short4v s;
      s[0]=(short)f2bf(v[0]); s[1]=(short)f2bf(v[1]);
      s[2]=(short)f2bf(v[2]); s[3]=(short)f2bf(v[3]);
      *(short4v*)&e_lds[i*EPITCH + c4] = s;
    }
  }
  __syncthreads();

  const float* bias = dir ? b_b : b_f;
  float4v acc[2][8];
  #pragma unroll
  for (int g = 0; g < 4; ++g)
    #pragma unroll
    for (int tj = 0; tj < 2; ++tj){
      float bv = bias[g*256 + wv*32 + tj*16 + lc];
      acc[0][g*2+tj] = (float4v){bv,bv,bv,bv};
      acc[1][g*2+tj] = acc[0][g*2+tj];
    }

  const short8* KP = (const short8*)kpack + (long)dir*64*4*64;
  #pragma unroll
  for (int ks = 0; ks < 4; ++ks){
    short8 a0 = *(const short8*)&e_lds[lc*EPITCH + ks*32 + q*8];
    short8 a1 = *(const short8*)&e_lds[(16+lc)*EPITCH + ks*32 + q*8];
    #pragma unroll
    for (int n = 0; n < 8; ++n){
      int g = n >> 1, tj = n & 1;
      int nt = g*16 + wv*2 + tj;
      short8 b = KP[(nt*4 + ks)*64 + lane];
      acc[0][n] = __builtin_amdgcn_mfma_f32_16x16x32_bf16(a0, b, acc[0][n], 0, 0, 0);
      acc[1][n] = __builtin_amdgcn_mfma_f32_16x16x32_bf16(a1, b, acc[1][n], 0, 0, 0);
    }
  }

  _Float16* xzb = xz + ((long)(dir*128 + bat))*NPOS*1024;
  #pragma unroll
  for (int mt = 0; mt < 2; ++mt)
    #pragma unroll
    for (int r = 0; r < 4; ++r){
      int row = mt*16 + q*4 + r;
      int p = pt*32 + row;
      if (p < NPOS){
        half8 hv;
        #pragma unroll
        for (int n = 0; n < 8; ++n) hv[n] = (_Float16)acc[mt][n][r];
        __builtin_nontemporal_store(hv, (half8*)(xzb + (long)p*1024 + wv*128 + lc*8));
      }
    }
}

// ---------------------------------------------------------------------------
// Recurrent kernel, M=64: block = (dir, batch-pair), 64 chains, grid 128.
// Halves the aggregate weight-stream demand (4.2 GB vs 8.4) — the one lever
// that has moved the measured ~6.8 TB/s fill-rate wall. Structure = round-2's
// validated shape: inline B loads (compiler-scheduled), h double-buffered in
// LDS (XOR chunk swizzle, conflict-free), ONE __syncthreads per step.
// Per-block K-slice phase rotation de-hotspots L2 banks (acc is ks-order
// invariant). 96 KB dynamic LDS forces 1 block/CU spread (128 CUs active).
// Gates in two mt-pair passes to cap xz register pressure (acc=128 VGPRs).
// ---------------------------------------------------------------------------
__launch_bounds__(512, 2)
__global__ void lstm_rec(const int* __restrict__ inputs, const _Float16* __restrict__ xz,
                         const unsigned short* __restrict__ rkpack,
                         const float* __restrict__ wci_f, const float* __restrict__ wcf_f,
                         const float* __restrict__ wco_f,
                         const float* __restrict__ wci_b, const float* __restrict__ wcf_b,
                         const float* __restrict__ wco_b,
                         float* __restrict__ h_out)
{
  extern __shared__ __align__(16) char smem[];
  short* h_lds = (short*)smem;   // [2][64*256] = 65536 B used (96 KB reserved)

  const int tid  = threadIdx.x;
  const int lane = tid & 63;
  const int wv   = tid >> 6;
  const int lc   = lane & 15;
  const int q    = lane >> 4;
  const int bid  = blockIdx.x;
  const int dir  = bid >> 6;
  const int bp   = bid & 63;
  const int b0   = bp*2, b1 = bp*2 + 1;
  const int phase = (bid*5) & 7;

  for (int i = tid; i < 2*64*256; i += 512) h_lds[i] = 0;

  // masks for both batches (ballot, no LDS)
  unsigned long long ma0 = __ballot(inputs[b0*NPOS + lane] != 0);
  unsigned long long ma1 = __ballot(inputs[b0*NPOS + 64 + lane] != 0);
  int p2 = 128 + lane;
  unsigned long long ma2 = __ballot((p2 < NPOS) && (inputs[b0*NPOS + p2] != 0));
  unsigned long long mb0 = __ballot(inputs[b1*NPOS + lane] != 0);
  unsigned long long mb1 = __ballot(inputs[b1*NPOS + 64 + lane] != 0);
  unsigned long long mb2 = __ballot((p2 < NPOS) && (inputs[b1*NPOS + p2] != 0));

  const float* wci = dir ? wci_b : wci_f;
  const float* wcf = dir ? wcf_b : wcf_f;
  const float* wco = dir ? wco_b : wco_f;
  float wcir[2], wcfr[2], wcor[2];
  #pragma unroll
  for (int tj = 0; tj < 2; ++tj){
    int j = wv*32 + tj*16 + lc;
    wcir[tj] = wci[j]; wcfr[tj] = wcf[j]; wcor[tj] = wco[j];
  }

  float hreg[4][4][2], creg[4][4][2];
  #pragma unroll
  for (int mt = 0; mt < 4; ++mt)
    #pragma unroll
    for (int rr = 0; rr < 4; ++rr)
      #pragma unroll
      for (int tj = 0; tj < 2; ++tj){ hreg[mt][rr][tj] = 0.f; creg[mt][rr][tj] = 0.f; }

  const short8*   RK   = (const short8*)rkpack + (long)dir*64*8*64;
  const _Float16* xzp0 = xz + ((long)(dir*128 + b0))*NPOS*1024 + wv*128 + lc*8;
  const _Float16* xzp1 = xz + ((long)(dir*128 + b1))*NPOS*1024 + wv*128 + lc*8;

  __syncthreads();

  for (int s = 0; s < 64; ++s){
    const int t = dir ? (63 - s) : s;
    const short* hr = &h_lds[(s & 1)*64*256];
    short*       hw = &h_lds[((s & 1) ^ 1)*64*256];

    float4v acc[4][8];
    #pragma unroll
    for (int mt = 0; mt < 4; ++mt)
      #pragma unroll
      for (int n = 0; n < 8; ++n) acc[mt][n] = (float4v){0.f,0.f,0.f,0.f};

    // K-loop, phase-rotated slice order (acc is order-invariant over ks)
    #pragma unroll
    for (int kk = 0; kk < 8; ++kk){
      const int ks = (kk + phase) & 7;
      short8 a[4];
      #pragma unroll
      for (int mt = 0; mt < 4; ++mt){
        int c = mt*16 + lc;
        a[mt] = *(const short8*)&hr[c*256 + (((4*ks + q) ^ (c & 31))*8)];
      }
      #pragma unroll
      for (int f = 0; f < 8; ++f){
        int g = f >> 1, tj = f & 1, nt = g*16 + wv*2 + tj;
        short8 b = RK[(nt*8 + ks)*64 + lane];
        acc[0][f] = __builtin_amdgcn_mfma_f32_16x16x32_bf16(a[0], b, acc[0][f], 0, 0, 0);
        acc[1][f] = __builtin_amdgcn_mfma_f32_16x16x32_bf16(a[1], b, acc[1][f], 0, 0, 0);
        acc[2][f] = __builtin_amdgcn_mfma_f32_16x16x32_bf16(a[2], b, acc[2][f], 0, 0, 0);
        acc[3][f] = __builtin_amdgcn_mfma_f32_16x16x32_bf16(a[3], b, acc[3][f], 0, 0, 0);
      }
    }

    // gates in two mt-pair passes (batch b0: mt 0,1; batch b1: mt 2,3)
    #pragma unroll
    for (int half = 0; half < 2; ++half){
      const _Float16* xzb = half ? xzp1 : xzp0;
      half8 xzr[2][4];
      #pragma unroll
      for (int sm = 0; sm < 2; ++sm)
        #pragma unroll
        for (int rr = 0; rr < 4; ++rr){
          int w = sm*16 + q*4 + rr;
          int p = (w == 0) ? t : 63 + w + t;
          xzr[sm][rr] = __builtin_nontemporal_load((const half8*)(xzb + (long)p*1024));
        }
      #pragma unroll
      for (int sm = 0; sm < 2; ++sm){
        const int mt = half*2 + sm;
        #pragma unroll
        for (int rr = 0; rr < 4; ++rr){
          int w = sm*16 + q*4 + rr;
          int p = (w == 0) ? t : 63 + w + t;
          unsigned long long mm = half
            ? ((p < 64) ? mb0 : ((p < 128) ? mb1 : mb2))
            : ((p < 64) ? ma0 : ((p < 128) ? ma1 : ma2));
          bool msk = (mm >> (p & 63)) & 1ull;
          #pragma unroll
          for (int tj = 0; tj < 2; ++tj){
            float zi = acc[mt][0+tj][rr] + (float)xzr[sm][rr][0+tj];
            float zf = acc[mt][2+tj][rr] + (float)xzr[sm][rr][2+tj];
            float zc = acc[mt][4+tj][rr] + (float)xzr[sm][rr][4+tj];
            float zo = acc[mt][6+tj][rr] + (float)xzr[sm][rr][6+tj];
            float c0 = creg[mt][rr][tj];
            float ig = fsig(zi + c0*wcir[tj]);
            float fg = fsig(zf + c0*wcfr[tj]);
            float cn = fg*c0 + ig*ftanh(zc);
            float og = fsig(zo + cn*wcor[tj]);
            float hn = og*ftanh(cn);
            float hv = msk ? hn : hreg[mt][rr][tj];
            float cv = msk ? cn : c0;
            hreg[mt][rr][tj] = hv;
            creg[mt][rr][tj] = cv;
            int c = mt*16 + q*4 + rr;
            int u = wv*4 + tj*2 + (lc >> 3);
            hw[c*256 + ((u ^ (c & 31))*8) + (lc & 7)] = (short)f2bf(hv);
          }
        }
      }
    }
    __syncthreads();   // one barrier per step (h double-buffered)
  }

  #pragma unroll
  for (int mt = 0; mt < 4; ++mt){
    int bat = (mt < 2) ? b0 : b1;
    #pragma unroll
    for (int rr = 0; rr < 4; ++rr){
      int w = (mt & 1)*16 + q*4 + rr;
      #pragma unroll
      for (int tj = 0; tj < 2; ++tj){
        int j = wv*32 + tj*16 + lc;
        __builtin_nontemporal_store(hreg[mt][rr][tj],
            &h_out[(((long)dir*128 + bat)*32 + w)*256 + j]);
      }
    }
  }
}

// ---------------------------------------------------------------------------
// h_avg = 0.5(h_f + h_b); cos = |q.d|/(|q||d|); softmax over 31 docs.
// ---------------------------------------------------------------------------
__global__ void finalize(const float* __restrict__ h_out, float* __restrict__ out){
  __shared__ float hav[32*256];
  __shared__ float dotl[32], sql[32];
  const int bat = blockIdx.x;
  const int tid = threadIdx.x;
  const float* hf = h_out + (long)bat*8192;
  const float* hb = h_out + (long)(128 + bat)*8192;
  for (int i = tid; i < 8192; i += 256) hav[i] = 0.5f*(hf[i] + hb[i]);
  __syncthreads();
  const int lane = tid & 63, wv = tid >> 6;
  for (int n = wv; n < 32; n += 4){
    float s1 = 0.f, s2 = 0.f;
    for (int j = lane; j < 256; j += 64){
      float a  = hav[n*256 + j];
      float qv = hav[j];
      s1 += a*qv; s2 += a*a;
    }
    #pragma unroll
    for (int off = 32; off; off >>= 1){
      s1 += __shfl_down(s1, off);
      s2 += __shfl_down(s2, off);
    }
    if (lane == 0){ dotl[n] = s1; sql[n] = s2; }
  }
  __syncthreads();
  if (wv == 0){
    float cosv = -1e30f;
    if (lane < 31)
      cosv = fabsf(dotl[lane+1]) / (sqrtf(sql[0]) * sqrtf(sql[lane+1]));
    float mx = cosv;
    #pragma unroll
    for (int off = 32; off; off >>= 1) mx = fmaxf(mx, __shfl_xor(mx, off));
    float e = (lane < 31) ? __expf(cosv - mx) : 0.f;
    float sum = e;
    #pragma unroll
    for (int off = 32; off; off >>= 1) sum += __shfl_xor(sum, off);
    if (lane < 31) out[bat*31 + lane] = e / sum;
  }
}

extern "C" void kernel_launch(void* const* d_in, const int* in_sizes, int n_in,
                              void* d_out, int out_size, void* d_ws, size_t ws_size,
                              hipStream_t stream) {
  const int*   inputs = (const int*)  d_in[0];
  const float* emb    = (const float*)d_in[1];
  const float* k_f    = (const float*)d_in[2];
  const float* rk_f   = (const float*)d_in[3];
  const float* b_f    = (const float*)d_in[4];
  const float* wci_f  = (const float*)d_in[5];
  const float* wcf_f  = (const float*)d_in[6];
  const float* wco_f  = (const float*)d_in[7];
  const float* k_b    = (const float*)d_in[8];
  const float* rk_b   = (const float*)d_in[9];
  const float* b_b    = (const float*)d_in[10];
  const float* wci_b  = (const float*)d_in[11];
  const float* wcf_b  = (const float*)d_in[12];
  const float* wco_b  = (const float*)d_in[13];

  unsigned short* rkp  = (unsigned short*)d_ws;
  unsigned short* kp   = (unsigned short*)((char*)d_ws + OFF_KP);
  _Float16*       xzp  = (_Float16*)     ((char*)d_ws + OFF_XZ);
  float*          hout = (float*)        ((char*)d_ws + OFF_HOUT);

  prepack<<<(RKP_SHORTS + KP_SHORTS)/256, 256, 0, stream>>>(k_f, rk_f, k_b, rk_b, rkp, kp);
  xzgemm <<<128*2*5, 512, 0, stream>>>(inputs, emb, kp, b_f, b_b, xzp);
  lstm_rec<<<128, 512, 98304, stream>>>(inputs, xzp, rkp,
                                        wci_f, wcf_f, wco_f,
                                        wci_b, wcf_b, wco_b, hout);
  finalize<<<128, 256, 0, stream>>>(hout, (float*)d_out);
}